// Round 15
// baseline (75.871 us; speedup 1.0000x reference)
//
#include <hip/hip_runtime.h>
#include <hip/hip_bf16.h>
#include <hip/hip_fp16.h>

// DenseGAT fused kernel for MI355X.
// N=4096, IN=256, HEADS=8, D=64, C=512.
// Round 15: split-K projection (2048 blocks of 16 rows x head; 4 waves each
// take a K-quarter, LDS-reduce, wave0 epilogue) interleaved with the mask
// stream via bid&1 -- proj was 512 blocks = 2/CU, latency-bound ~27us tail.
// ftab/attn unchanged from R14.
//
// ws layout:
//   Hpack : _Float16 [8][128][4][64][8] @ 0        (4 MB)  H in B-frag order
//   maskw : uint     [4096][128]        @ 4M       (2 MB)  bit j&31 of word j>>5
//   ddata : float    [8][4096]          @ 6M       (128 KB) e_dst*log2e
//   esrc  : float    [4096][8]          @ 6M+128K  (128 KB)
//   Epk1  : uint     [8][4096]          @ 6M+256K  (128 KB) {E1,E1} f16x2
//   Epk2  : uint     [8][4096]          @ 6M+384K  (128 KB)
//   F1    : _Float16 [8][4096]          @ 6M+512K  (64 KB)
//   F2    : _Float16 [8][4096]          @ 6M+576K  (64 KB)

#define GAT_N 4096
#define GAT_K 256
#define GAT_C 512
#define GAT_H 8
#define L2E 1.4426950408889634f
#define LN2 0.6931471805599453f

typedef _Float16 v8h __attribute__((ext_vector_type(8)));
typedef _Float16 f16x2 __attribute__((ext_vector_type(2)));
typedef float v4f __attribute__((ext_vector_type(4)));
typedef int v4i __attribute__((ext_vector_type(4)));

union U8 { v4i w; v8h h; };

static __device__ inline v4f mfma16(v8h a, v8h b, v4f c) {
    return __builtin_amdgcn_mfma_f32_16x16x32_f16(a, b, c, 0, 0, 0);
}

static __device__ inline unsigned pmax2(f16x2 e1, f16x2 e2, int f1w, int f2w) {
    f16x2 f1 = __builtin_bit_cast(f16x2, f1w);
    f16x2 f2 = __builtin_bit_cast(f16x2, f2w);
    f16x2 p1 = e1 * f1;
    f16x2 p2 = e2 * f2;
    f16x2 mx = __builtin_elementwise_max(p1, p2);
    return __builtin_bit_cast(unsigned, mx);
}

// -------- Phase A: mask (even bids) + split-K projection (odd bids) ----------
// grid 4096: bid&1==0 -> mask (2048 blocks), bid&1==1 -> proj (2048 blocks).
__global__ __launch_bounds__(256) void gat_prep(
    const float* __restrict__ x, const float* __restrict__ W,
    const float* __restrict__ asrc, const float* __restrict__ adst,
    const int* __restrict__ adj,
    _Float16* __restrict__ Hpack, float* __restrict__ ddata,
    float* __restrict__ esrc, unsigned* __restrict__ maskw)
{
    __shared__ float red[3][64][17];    // 12.9 KB split-K partial exchange
    const int bid = blockIdx.x;
    const int tid = threadIdx.x;

    if ((bid & 1) == 0) {
        // ---- mask path: lane covers 8 consecutive ints per iter; ALL loads
        // issued before any shfl (8 KB in flight per wave). Plain cached loads.
        const int g = (bid >> 1) * 4 + (tid >> 6);      // wave 0..8191
        const int lane = tid & 63;
        const size_t base = (size_t)g * 2048;           // flat int index
        const int* pa = adj + base + (size_t)lane * 8;
        v4i v[8];
#pragma unroll
        for (int i = 0; i < 4; ++i) {
            v[2 * i]     = *(const v4i*)(pa + (size_t)i * 512);
            v[2 * i + 1] = *(const v4i*)(pa + (size_t)i * 512 + 4);
        }
#pragma unroll
        for (int i = 0; i < 4; ++i) {
            v4i a = v[2 * i], b = v[2 * i + 1];
            unsigned bits = (unsigned)(a.x > 0)        | ((unsigned)(a.y > 0) << 1)
                          | ((unsigned)(a.z > 0) << 2) | ((unsigned)(a.w > 0) << 3)
                          | ((unsigned)(b.x > 0) << 4) | ((unsigned)(b.y > 0) << 5)
                          | ((unsigned)(b.z > 0) << 6) | ((unsigned)(b.w > 0) << 7);
            unsigned w = bits << ((lane & 3) * 8);
            w |= __shfl_xor(w, 1);
            w |= __shfl_xor(w, 2);
            if ((lane & 3) == 0) maskw[(base >> 5) + i * 16 + (lane >> 2)] = w;
        }
        return;
    }

    // ---- projection path: 16 rows x head per block; wave wv = K-quarter ----
    const int pb = bid >> 1;                            // 0..2047
    const int head = pb & 7, t16 = pb >> 3;             // t16: 16-row tile
    const int wv = tid >> 6, l = tid & 63;
    const int dlow = l & 15, q = l >> 4;
    const int rowbase = t16 * 16;
    const int arow = rowbase + dlow;

    v4f acc[4] = {};
#pragma unroll
    for (int kc2 = 0; kc2 < 2; ++kc2) {
        const int k0 = (wv * 2 + kc2) * 32 + q * 8;
        const float4* ap = (const float4*)(x + (size_t)arow * GAT_K + k0);
        float4 xa = ap[0], xb = ap[1];
        v8h af;
        af[0] = (_Float16)xa.x; af[1] = (_Float16)xa.y; af[2] = (_Float16)xa.z; af[3] = (_Float16)xa.w;
        af[4] = (_Float16)xb.x; af[5] = (_Float16)xb.y; af[6] = (_Float16)xb.z; af[7] = (_Float16)xb.w;
#pragma unroll
        for (int nt = 0; nt < 4; ++nt) {
            const int c = head * 64 + nt * 16 + dlow;
            const float4* bp = (const float4*)(W + (size_t)c * GAT_K + k0);
            float4 wa = bp[0], wb = bp[1];
            v8h bf;
            bf[0] = (_Float16)wa.x; bf[1] = (_Float16)wa.y; bf[2] = (_Float16)wa.z; bf[3] = (_Float16)wa.w;
            bf[4] = (_Float16)wb.x; bf[5] = (_Float16)wb.y; bf[6] = (_Float16)wb.z; bf[7] = (_Float16)wb.w;
            acc[nt] = mfma16(af, bf, acc[nt]);
        }
    }

    // split-K combine: waves 1..3 write partials, wave 0 reduces + epilogue
    if (wv != 0) {
        float* rp = &red[wv - 1][l][0];
#pragma unroll
        for (int nt = 0; nt < 4; ++nt)
#pragma unroll
            for (int r = 0; r < 4; ++r) rp[nt * 4 + r] = acc[nt][r];
    }
    __syncthreads();
    if (wv != 0) return;
#pragma unroll
    for (int p = 0; p < 3; ++p) {
        const float* rp = &red[p][l][0];
#pragma unroll
        for (int nt = 0; nt < 4; ++nt)
#pragma unroll
            for (int r = 0; r < 4; ++r) acc[nt][r] += rp[nt * 4 + r];
    }

    float as[4], ad[4];
#pragma unroll
    for (int nt = 0; nt < 4; ++nt) {
        const int d = nt * 16 + dlow;
        as[nt] = asrc[head * 64 + d];
        ad[nt] = adst[head * 64 + d];
    }
    float es[4], ed[4];
#pragma unroll
    for (int r = 0; r < 4; ++r) {
        float se = 0.f, de = 0.f;
#pragma unroll
        for (int nt = 0; nt < 4; ++nt) { se += acc[nt][r] * as[nt]; de += acc[nt][r] * ad[nt]; }
#pragma unroll
        for (int m = 1; m < 16; m <<= 1) { se += __shfl_xor(se, m); de += __shfl_xor(de, m); }
        es[r] = se; ed[r] = de;
    }
    if (dlow == 0) {
#pragma unroll
        for (int r = 0; r < 4; ++r) {
            const int j = rowbase + q * 4 + r;
            esrc[j * GAT_H + head] = es[r];
            ddata[(size_t)head * GAT_N + j] = ed[r] * L2E;
        }
    }

    // Hpack: element (j, d) -> [head][j>>5][nt][(p>>3)*16 + dlow][p&7], p=j&31.
    const int jc = rowbase >> 5;
    const int p16 = rowbase & 16;
#pragma unroll
    for (int nt = 0; nt < 4; ++nt) {
#pragma unroll
        for (int rp2 = 0; rp2 < 4; rp2 += 2) {
            const int p = p16 + q * 4 + rp2;
            const int qp = p >> 3, e = p & 7;
            const int lanep = qp * 16 + dlow;
            const size_t idx = ((((size_t)head * 128 + jc) * 4 + nt) * 64 + lanep) * 8 + e;
            union { unsigned u; _Float16 h[2]; } pk;
            pk.h[0] = (_Float16)acc[nt][rp2];
            pk.h[1] = (_Float16)acc[nt][rp2 + 1];
            *(unsigned*)(Hpack + idx) = pk.u;
        }
    }
}

// -------- Phase A2: per-i and per-j exponential factor tables ---------------
// grid 128 = 8 heads x 16 slices; per-head max reduced redundantly per block.
__global__ __launch_bounds__(256) void gat_ftab(
    const float* __restrict__ esrc, const float* __restrict__ ddata,
    unsigned* __restrict__ Epk1, unsigned* __restrict__ Epk2,
    _Float16* __restrict__ F1, _Float16* __restrict__ F2)
{
    __shared__ float wmax[4];
    const int bid = blockIdx.x;
    const int tid = threadIdx.x;
    const int head = bid >> 4;
    const float* dh = ddata + head * GAT_N;

    float m = -3.4e38f;
    {
        const v4f* dp = (const v4f*)(dh + tid * 16);
#pragma unroll
        for (int k = 0; k < 4; ++k) {
            v4f v = dp[k];
            m = fmaxf(m, fmaxf(fmaxf(v[0], v[1]), fmaxf(v[2], v[3])));
        }
    }
#pragma unroll
    for (int s = 1; s < 64; s <<= 1) m = fmaxf(m, __shfl_xor(m, s));
    if ((tid & 63) == 0) wmax[tid >> 6] = m;
    __syncthreads();
    const float Dml = fmaxf(fmaxf(wmax[0], wmax[1]), fmaxf(wmax[2], wmax[3]));
    const float Dm = Dml * LN2;

    const int i = (bid & 15) * 256 + tid;
    const int idx = head * GAT_N + i;
    const float s = esrc[i * GAT_H + head];
    const float sm = s + Dm;
    const float M = fmaxf(sm, 0.2f * sm);
    const float e1 = __builtin_amdgcn_exp2f((sm - M) * L2E);
    const float e2 = __builtin_amdgcn_exp2f((0.2f * sm - M) * L2E);
    union { _Float16 h[2]; unsigned u; } pk;
    pk.h[0] = (_Float16)e1; pk.h[1] = (_Float16)e1; Epk1[idx] = pk.u;
    pk.h[0] = (_Float16)e2; pk.h[1] = (_Float16)e2; Epk2[idx] = pk.u;
    const float dl = dh[i] - Dml;
    F1[idx] = (_Float16)__builtin_amdgcn_exp2f(dl);
    F2[idx] = (_Float16)__builtin_amdgcn_exp2f(0.2f * dl);
}

// ---------------- Phase B: fused mask + softmax + alpha@H -------------------
// grid 512 = (it = bid>>3, 64 rows) x (head = bid&7 -> XCD-pinned).
// block 256 (4 waves), wave wv -> jc%4==wv. H double-buffered; mask/F
// single-buffered. (256,3): 12 waves/CU. Unchanged from R14.
__global__ __launch_bounds__(256, 3) void gat_attn(
    const unsigned* __restrict__ maskw, const _Float16* __restrict__ Hpack,
    const unsigned* __restrict__ Epk1, const unsigned* __restrict__ Epk2,
    const _Float16* __restrict__ F1, const _Float16* __restrict__ F2,
    const float* __restrict__ bias, float* __restrict__ out)
{
    __shared__ __align__(16) char smem[2 * 64 * 81 * 4];
    unsigned (*mlds)[132] = (unsigned (*)[132])smem;
    float* xch = (float*)smem;

    const int bid = blockIdx.x;
    const int head = bid & 7;
    const int it = bid >> 3;
    const int tid = threadIdx.x;
    const int wv = tid >> 6, l = tid & 63;
    const int dlow = l & 15, q = l >> 4, qs = q * 8;
    const int ibase = it * 64;

    {
        const int r = tid >> 2;
        const int wq = (tid & 3) * 32;
        const unsigned* mp = maskw + (size_t)(ibase + r) * 128 + wq;
#pragma unroll
        for (int k = 0; k < 8; ++k) {
            v4i a = *(const v4i*)(mp + k * 4);
            *(v4i*)&mlds[r][wq + k * 4] = a;
        }
    }

    f16x2 E1p[4], E2p[4];
#pragma unroll
    for (int g = 0; g < 4; ++g) {
        E1p[g] = __builtin_bit_cast(f16x2, Epk1[head * GAT_N + ibase + g * 16 + dlow]);
        E2p[g] = __builtin_bit_cast(f16x2, Epk2[head * GAT_N + ibase + g * 16 + dlow]);
    }

    v4f accW[4][4] = {};
    v4f accZ[4] = {};
    v8h ones;
#pragma unroll
    for (int e = 0; e < 8; ++e) ones[e] = (_Float16)1.0f;

    const _Float16* Hl = Hpack + (size_t)head * 262144 + (size_t)l * 8;
    const _Float16* F1h = F1 + head * GAT_N;
    const _Float16* F2h = F2 + head * GAT_N;

    __syncthreads();

    v8h Ah[4], Bh[4];

#define GAT_LOADH(P, T) {                                                    \
        const _Float16* hp_ = Hl + (size_t)((T) * 4 + wv) * 2048;            \
        P##h[0] = *(const v8h*)(hp_);                                        \
        P##h[1] = *(const v8h*)(hp_ + 512);                                  \
        P##h[2] = *(const v8h*)(hp_ + 1024);                                 \
        P##h[3] = *(const v8h*)(hp_ + 1536);                                 \
    }

#define GAT_COMP(P, T) {                                                     \
        const int jc_ = (T) * 4 + wv;                                        \
        const int kg_ = (jc_ << 5) + qs;                                     \
        const v4i f1_ = *(const v4i*)(F1h + kg_);                            \
        const v4i f2_ = *(const v4i*)(F2h + kg_);                            \
        _Pragma("unroll")                                                    \
        for (int g = 0; g < 4; ++g) {                                        \
            const unsigned mw_ = mlds[g * 16 + dlow][jc_];                   \
            const unsigned b8_ = (mw_ >> qs) & 255u;                         \
            const unsigned z1_ = (((b8_ & 15u) * 0x204081u) << 7) & 0x80808080u; \
            const unsigned z2_ = (((b8_ >> 4) * 0x204081u) << 7) & 0x80808080u;  \
            const unsigned m1_ = (z1_ >> 7) * 255u;                          \
            const unsigned m2_ = (z2_ >> 7) * 255u;                          \
            U8 fr_;                                                          \
            fr_.w[0] = (int)(pmax2(E1p[g], E2p[g], f1_[0], f2_[0])           \
                             & __builtin_amdgcn_perm(0u, m1_, 0x01010000u)); \
            fr_.w[1] = (int)(pmax2(E1p[g], E2p[g], f1_[1], f2_[1])           \
                             & __builtin_amdgcn_perm(0u, m1_, 0x03030202u)); \
            fr_.w[2] = (int)(pmax2(E1p[g], E2p[g], f1_[2], f2_[2])           \
                             & __builtin_amdgcn_perm(0u, m2_, 0x01010000u)); \
            fr_.w[3] = (int)(pmax2(E1p[g], E2p[g], f1_[3], f2_[3])           \
                             & __builtin_amdgcn_perm(0u, m2_, 0x03030202u)); \
            accW[g][0] = mfma16(fr_.h, P##h[0], accW[g][0]);                 \
            accW[g][1] = mfma16(fr_.h, P##h[1], accW[g][1]);                 \
            accW[g][2] = mfma16(fr_.h, P##h[2], accW[g][2]);                 \
            accW[g][3] = mfma16(fr_.h, P##h[3], accW[g][3]);                 \
            accZ[g]    = mfma16(fr_.h, ones,  accZ[g]);                      \
        }                                                                    \
    }

    GAT_LOADH(A, 0)
    for (int t = 0; t < 30; t += 2) {
        GAT_LOADH(B, t + 1)
        GAT_COMP(A, t)
        GAT_LOADH(A, t + 2)
        GAT_COMP(B, t + 1)
    }
    GAT_LOADH(B, 31)
    GAT_COMP(A, 30)
    GAT_COMP(B, 31)
#undef GAT_LOADH
#undef GAT_COMP

    __syncthreads();
    {
        float* xb = xch + ((size_t)(wv >> 1) * 64 + l) * 81;
        if (wv & 1) {
#pragma unroll
            for (int g = 0; g < 4; ++g) {
#pragma unroll
                for (int nt = 0; nt < 4; ++nt)
#pragma unroll
                    for (int r = 0; r < 4; ++r) xb[(g * 4 + nt) * 4 + r] = accW[g][nt][r];
#pragma unroll
                for (int r = 0; r < 4; ++r) xb[64 + g * 4 + r] = accZ[g][r];
            }
        }
        __syncthreads();
        if (!(wv & 1)) {
#pragma unroll
            for (int g = 0; g < 4; ++g) {
#pragma unroll
                for (int nt = 0; nt < 4; ++nt)
#pragma unroll
                    for (int r = 0; r < 4; ++r) accW[g][nt][r] += xb[(g * 4 + nt) * 4 + r];
#pragma unroll
                for (int r = 0; r < 4; ++r) accZ[g][r] += xb[64 + g * 4 + r];
            }
        }
        __syncthreads();
        float* x0 = xch + (size_t)l * 81;
        if (wv == 2) {
#pragma unroll
            for (int g = 0; g < 4; ++g) {
#pragma unroll
                for (int nt = 0; nt < 4; ++nt)
#pragma unroll
                    for (int r = 0; r < 4; ++r) x0[(g * 4 + nt) * 4 + r] = accW[g][nt][r];
#pragma unroll
                for (int r = 0; r < 4; ++r) x0[64 + g * 4 + r] = accZ[g][r];
            }
        }
        __syncthreads();
        if (wv == 0) {
#pragma unroll
            for (int g = 0; g < 4; ++g) {
#pragma unroll
                for (int nt = 0; nt < 4; ++nt)
#pragma unroll
                    for (int r = 0; r < 4; ++r) accW[g][nt][r] += x0[(g * 4 + nt) * 4 + r];
#pragma unroll
                for (int r = 0; r < 4; ++r) accZ[g][r] += x0[64 + g * 4 + r];
            }
#pragma unroll
            for (int g = 0; g < 4; ++g) {
                float zi[4];
#pragma unroll
                for (int r = 0; r < 4; ++r) zi[r] = 1.0f / accZ[g][r];
#pragma unroll
                for (int nt = 0; nt < 4; ++nt) {
                    const int col = head * 64 + nt * 16 + dlow;
                    const float b = bias[col];
#pragma unroll
                    for (int r = 0; r < 4; ++r) {
                        const int row = ibase + g * 16 + q * 4 + r;
                        out[(size_t)row * GAT_C + col] = accW[g][nt][r] * zi[r] + b;
                    }
                }
            }
        }
    }
}

extern "C" void kernel_launch(void* const* d_in, const int* in_sizes, int n_in,
                              void* d_out, int out_size, void* d_ws, size_t ws_size,
                              hipStream_t stream) {
    const float* x    = (const float*)d_in[0];
    const int*   adj  = (const int*)d_in[1];
    const float* W    = (const float*)d_in[2];
    const float* asrc = (const float*)d_in[3];
    const float* adst = (const float*)d_in[4];
    const float* bias = (const float*)d_in[5];
    float* out = (float*)d_out;

    char* ws = (char*)d_ws;                     // needs ~6.7 MB
    _Float16* Hpack  = (_Float16*)ws;                               // 4 MB
    unsigned* maskw  = (unsigned*)(ws + (4u << 20));                // 2 MB
    float*    ddata  = (float*)(ws + (6u << 20));                   // 128 KB
    float*    esrc   = (float*)(ws + (6u << 20) + (128u << 10));    // 128 KB
    unsigned* Epk1   = (unsigned*)(ws + (6u << 20) + (256u << 10)); // 128 KB
    unsigned* Epk2   = (unsigned*)(ws + (6u << 20) + (384u << 10)); // 128 KB
    _Float16* F1     = (_Float16*)(ws + (6u << 20) + (512u << 10)); // 64 KB
    _Float16* F2     = (_Float16*)(ws + (6u << 20) + (576u << 10)); // 64 KB

    hipLaunchKernelGGL(gat_prep, dim3(4096), dim3(256), 0, stream,
                       x, W, asrc, adst, adj, Hpack, ddata, esrc, maskw);
    hipLaunchKernelGGL(gat_ftab, dim3(128), dim3(256), 0, stream,
                       esrc, ddata, Epk1, Epk2, F1, F2);
    hipLaunchKernelGGL(gat_attn, dim3(512), dim3(256), 0, stream,
                       maskw, Hpack, Epk1, Epk2, F1, F2, bias, out);
}

// Round 16
// 63.115 us; speedup vs baseline: 1.2021x; 1.2021x over previous
//
#include <hip/hip_runtime.h>
#include <hip/hip_bf16.h>
#include <hip/hip_fp16.h>

// DenseGAT fused kernel for MI355X.
// N=4096, IN=256, HEADS=8, D=64, C=512.
// Round 16: R14 (best-known: 64.9us) + f16 W pre-convert (gat_wcvt, proven
// in R13). proj inner loop: 1x16B Wh load + MFMA per nt (was 2x16B f32 +
// 4 cvt). Everything else byte-identical to R14.
//
// ws layout:
//   Hpack : _Float16 [8][128][4][64][8] @ 0        (4 MB)  H in B-frag order
//   maskw : uint     [4096][128]        @ 4M       (2 MB)  bit j&31 of word j>>5
//   ddata : float    [8][4096]          @ 6M       (128 KB) e_dst*log2e
//   esrc  : float    [4096][8]          @ 6M+128K  (128 KB)
//   Epk1  : uint     [8][4096]          @ 6M+256K  (128 KB) {E1,E1} f16x2
//   Epk2  : uint     [8][4096]          @ 6M+384K  (128 KB)
//   F1    : _Float16 [8][4096]          @ 6M+512K  (64 KB)
//   F2    : _Float16 [8][4096]          @ 6M+576K  (64 KB)
//   Wh    : _Float16 [512][256]         @ 6M+640K  (256 KB)

#define GAT_N 4096
#define GAT_K 256
#define GAT_C 512
#define GAT_H 8
#define L2E 1.4426950408889634f
#define LN2 0.6931471805599453f

typedef _Float16 v8h __attribute__((ext_vector_type(8)));
typedef _Float16 f16x2 __attribute__((ext_vector_type(2)));
typedef float v4f __attribute__((ext_vector_type(4)));
typedef int v4i __attribute__((ext_vector_type(4)));

union U8 { v4i w; v8h h; };

static __device__ inline v4f mfma16(v8h a, v8h b, v4f c) {
    return __builtin_amdgcn_mfma_f32_16x16x32_f16(a, b, c, 0, 0, 0);
}

static __device__ inline unsigned pmax2(f16x2 e1, f16x2 e2, int f1w, int f2w) {
    f16x2 f1 = __builtin_bit_cast(f16x2, f1w);
    f16x2 f2 = __builtin_bit_cast(f16x2, f2w);
    f16x2 p1 = e1 * f1;
    f16x2 p2 = e2 * f2;
    f16x2 mx = __builtin_elementwise_max(p1, p2);
    return __builtin_bit_cast(unsigned, mx);
}

// -------- Phase A0: W f32 -> f16 pre-convert (64 blocks, proven R13) --------
__global__ __launch_bounds__(256) void gat_wcvt(
    const float* __restrict__ W, _Float16* __restrict__ Wh)
{
    const int idx = (blockIdx.x * 256 + threadIdx.x) * 8;
    const float4 a = *(const float4*)(W + idx);
    const float4 b = *(const float4*)(W + idx + 4);
    v8h h;
    h[0] = (_Float16)a.x; h[1] = (_Float16)a.y; h[2] = (_Float16)a.z; h[3] = (_Float16)a.w;
    h[4] = (_Float16)b.x; h[5] = (_Float16)b.y; h[6] = (_Float16)b.z; h[7] = (_Float16)b.w;
    *(v8h*)(Wh + idx) = h;
}

// -------- Phase A: projection (bid 0..511, dispatched first) + mask build ----
__global__ __launch_bounds__(256) void gat_prep(
    const float* __restrict__ x, const _Float16* __restrict__ Wh,
    const float* __restrict__ asrc, const float* __restrict__ adst,
    const int* __restrict__ adj,
    _Float16* __restrict__ Hpack, float* __restrict__ ddata,
    float* __restrict__ esrc, unsigned* __restrict__ maskw)
{
    const int bid = blockIdx.x;
    const int tid = threadIdx.x;

    if (bid >= 512) {
        // ---- mask path: lane covers 8 consecutive ints; ALL loads issued
        // before any shfl (8 KB in flight per wave). Plain cached loads.
        const int g = (bid - 512) * 4 + (tid >> 6);     // wave 0..8191
        const int lane = tid & 63;
        const size_t base = (size_t)g * 2048;           // flat int index
        const int* pa = adj + base + (size_t)lane * 8;
        v4i v[8];
#pragma unroll
        for (int i = 0; i < 4; ++i) {
            v[2 * i]     = *(const v4i*)(pa + (size_t)i * 512);
            v[2 * i + 1] = *(const v4i*)(pa + (size_t)i * 512 + 4);
        }
#pragma unroll
        for (int i = 0; i < 4; ++i) {
            v4i a = v[2 * i], b = v[2 * i + 1];
            unsigned bits = (unsigned)(a.x > 0)        | ((unsigned)(a.y > 0) << 1)
                          | ((unsigned)(a.z > 0) << 2) | ((unsigned)(a.w > 0) << 3)
                          | ((unsigned)(b.x > 0) << 4) | ((unsigned)(b.y > 0) << 5)
                          | ((unsigned)(b.z > 0) << 6) | ((unsigned)(b.w > 0) << 7);
            unsigned w = bits << ((lane & 3) * 8);
            w |= __shfl_xor(w, 1);
            w |= __shfl_xor(w, 2);
            if ((lane & 3) == 0) maskw[(base >> 5) + i * 16 + (lane >> 2)] = w;
        }
        return;
    }

    // ---- projection path (f16 W: 1x16B load + MFMA per nt) ----
    const int head = bid & 7, mtile = bid >> 3;
    const int wv = tid >> 6, l = tid & 63;
    const int dlow = l & 15, q = l >> 4;
    const int rowbase = mtile * 64 + wv * 16;
    const int arow = rowbase + dlow;

    v4f acc[4] = {};
#pragma unroll
    for (int kc = 0; kc < 8; ++kc) {
        const int k0 = kc * 32 + q * 8;
        const float4* ap = (const float4*)(x + (size_t)arow * GAT_K + k0);
        float4 xa = ap[0], xb = ap[1];
        v8h af;
        af[0] = (_Float16)xa.x; af[1] = (_Float16)xa.y; af[2] = (_Float16)xa.z; af[3] = (_Float16)xa.w;
        af[4] = (_Float16)xb.x; af[5] = (_Float16)xb.y; af[6] = (_Float16)xb.z; af[7] = (_Float16)xb.w;
#pragma unroll
        for (int nt = 0; nt < 4; ++nt) {
            const int c = head * 64 + nt * 16 + dlow;
            const v8h bf = *(const v8h*)(Wh + (size_t)c * GAT_K + k0);
            acc[nt] = mfma16(af, bf, acc[nt]);
        }
    }

    float as[4], ad[4];
#pragma unroll
    for (int nt = 0; nt < 4; ++nt) {
        const int d = nt * 16 + dlow;
        as[nt] = asrc[head * 64 + d];
        ad[nt] = adst[head * 64 + d];
    }
    float es[4], ed[4];
#pragma unroll
    for (int r = 0; r < 4; ++r) {
        float se = 0.f, de = 0.f;
#pragma unroll
        for (int nt = 0; nt < 4; ++nt) { se += acc[nt][r] * as[nt]; de += acc[nt][r] * ad[nt]; }
#pragma unroll
        for (int m = 1; m < 16; m <<= 1) { se += __shfl_xor(se, m); de += __shfl_xor(de, m); }
        es[r] = se; ed[r] = de;
    }
    if (dlow == 0) {
#pragma unroll
        for (int r = 0; r < 4; ++r) {
            const int j = rowbase + q * 4 + r;
            esrc[j * GAT_H + head] = es[r];
            ddata[(size_t)head * GAT_N + j] = ed[r] * L2E;
        }
    }

    // Hpack: element (j, d) -> [head][j>>5][nt][(p>>3)*16 + dlow][p&7], p=j&31.
    const int jc = rowbase >> 5;
    const int p16 = rowbase & 16;
#pragma unroll
    for (int nt = 0; nt < 4; ++nt) {
#pragma unroll
        for (int rp = 0; rp < 4; rp += 2) {
            const int p = p16 + q * 4 + rp;
            const int qp = p >> 3, e = p & 7;
            const int lanep = qp * 16 + dlow;
            const size_t idx = ((((size_t)head * 128 + jc) * 4 + nt) * 64 + lanep) * 8 + e;
            union { unsigned u; _Float16 h[2]; } pk;
            pk.h[0] = (_Float16)acc[nt][rp];
            pk.h[1] = (_Float16)acc[nt][rp + 1];
            *(unsigned*)(Hpack + idx) = pk.u;
        }
    }
}

// -------- Phase A2: per-i and per-j exponential factor tables ---------------
// grid 128 = 8 heads x 16 slices; per-head max reduced redundantly per block.
__global__ __launch_bounds__(256) void gat_ftab(
    const float* __restrict__ esrc, const float* __restrict__ ddata,
    unsigned* __restrict__ Epk1, unsigned* __restrict__ Epk2,
    _Float16* __restrict__ F1, _Float16* __restrict__ F2)
{
    __shared__ float wmax[4];
    const int bid = blockIdx.x;
    const int tid = threadIdx.x;
    const int head = bid >> 4;
    const float* dh = ddata + head * GAT_N;

    float m = -3.4e38f;
    {
        const v4f* dp = (const v4f*)(dh + tid * 16);
#pragma unroll
        for (int k = 0; k < 4; ++k) {
            v4f v = dp[k];
            m = fmaxf(m, fmaxf(fmaxf(v[0], v[1]), fmaxf(v[2], v[3])));
        }
    }
#pragma unroll
    for (int s = 1; s < 64; s <<= 1) m = fmaxf(m, __shfl_xor(m, s));
    if ((tid & 63) == 0) wmax[tid >> 6] = m;
    __syncthreads();
    const float Dml = fmaxf(fmaxf(wmax[0], wmax[1]), fmaxf(wmax[2], wmax[3]));
    const float Dm = Dml * LN2;

    const int i = (bid & 15) * 256 + tid;
    const int idx = head * GAT_N + i;
    const float s = esrc[i * GAT_H + head];
    const float sm = s + Dm;
    const float M = fmaxf(sm, 0.2f * sm);
    const float e1 = __builtin_amdgcn_exp2f((sm - M) * L2E);
    const float e2 = __builtin_amdgcn_exp2f((0.2f * sm - M) * L2E);
    union { _Float16 h[2]; unsigned u; } pk;
    pk.h[0] = (_Float16)e1; pk.h[1] = (_Float16)e1; Epk1[idx] = pk.u;
    pk.h[0] = (_Float16)e2; pk.h[1] = (_Float16)e2; Epk2[idx] = pk.u;
    const float dl = dh[i] - Dml;
    F1[idx] = (_Float16)__builtin_amdgcn_exp2f(dl);
    F2[idx] = (_Float16)__builtin_amdgcn_exp2f(0.2f * dl);
}

// ---------------- Phase B: fused mask + softmax + alpha@H -------------------
// grid 512 = (it = bid>>3, 64 rows) x (head = bid&7 -> XCD-pinned).
// block 256 (4 waves), wave wv -> jc%4==wv. H double-buffered; mask/F
// single-buffered. (256,3): 12 waves/CU. Unchanged from R14.
__global__ __launch_bounds__(256, 3) void gat_attn(
    const unsigned* __restrict__ maskw, const _Float16* __restrict__ Hpack,
    const unsigned* __restrict__ Epk1, const unsigned* __restrict__ Epk2,
    const _Float16* __restrict__ F1, const _Float16* __restrict__ F2,
    const float* __restrict__ bias, float* __restrict__ out)
{
    __shared__ __align__(16) char smem[2 * 64 * 81 * 4];
    unsigned (*mlds)[132] = (unsigned (*)[132])smem;
    float* xch = (float*)smem;

    const int bid = blockIdx.x;
    const int head = bid & 7;
    const int it = bid >> 3;
    const int tid = threadIdx.x;
    const int wv = tid >> 6, l = tid & 63;
    const int dlow = l & 15, q = l >> 4, qs = q * 8;
    const int ibase = it * 64;

    {
        const int r = tid >> 2;
        const int wq = (tid & 3) * 32;
        const unsigned* mp = maskw + (size_t)(ibase + r) * 128 + wq;
#pragma unroll
        for (int k = 0; k < 8; ++k) {
            v4i a = *(const v4i*)(mp + k * 4);
            *(v4i*)&mlds[r][wq + k * 4] = a;
        }
    }

    f16x2 E1p[4], E2p[4];
#pragma unroll
    for (int g = 0; g < 4; ++g) {
        E1p[g] = __builtin_bit_cast(f16x2, Epk1[head * GAT_N + ibase + g * 16 + dlow]);
        E2p[g] = __builtin_bit_cast(f16x2, Epk2[head * GAT_N + ibase + g * 16 + dlow]);
    }

    v4f accW[4][4] = {};
    v4f accZ[4] = {};
    v8h ones;
#pragma unroll
    for (int e = 0; e < 8; ++e) ones[e] = (_Float16)1.0f;

    const _Float16* Hl = Hpack + (size_t)head * 262144 + (size_t)l * 8;
    const _Float16* F1h = F1 + head * GAT_N;
    const _Float16* F2h = F2 + head * GAT_N;

    __syncthreads();

    v8h Ah[4], Bh[4];

#define GAT_LOADH(P, T) {                                                    \
        const _Float16* hp_ = Hl + (size_t)((T) * 4 + wv) * 2048;            \
        P##h[0] = *(const v8h*)(hp_);                                        \
        P##h[1] = *(const v8h*)(hp_ + 512);                                  \
        P##h[2] = *(const v8h*)(hp_ + 1024);                                 \
        P##h[3] = *(const v8h*)(hp_ + 1536);                                 \
    }

#define GAT_COMP(P, T) {                                                     \
        const int jc_ = (T) * 4 + wv;                                        \
        const int kg_ = (jc_ << 5) + qs;                                     \
        const v4i f1_ = *(const v4i*)(F1h + kg_);                            \
        const v4i f2_ = *(const v4i*)(F2h + kg_);                            \
        _Pragma("unroll")                                                    \
        for (int g = 0; g < 4; ++g) {                                        \
            const unsigned mw_ = mlds[g * 16 + dlow][jc_];                   \
            const unsigned b8_ = (mw_ >> qs) & 255u;                         \
            const unsigned z1_ = (((b8_ & 15u) * 0x204081u) << 7) & 0x80808080u; \
            const unsigned z2_ = (((b8_ >> 4) * 0x204081u) << 7) & 0x80808080u;  \
            const unsigned m1_ = (z1_ >> 7) * 255u;                          \
            const unsigned m2_ = (z2_ >> 7) * 255u;                          \
            U8 fr_;                                                          \
            fr_.w[0] = (int)(pmax2(E1p[g], E2p[g], f1_[0], f2_[0])           \
                             & __builtin_amdgcn_perm(0u, m1_, 0x01010000u)); \
            fr_.w[1] = (int)(pmax2(E1p[g], E2p[g], f1_[1], f2_[1])           \
                             & __builtin_amdgcn_perm(0u, m1_, 0x03030202u)); \
            fr_.w[2] = (int)(pmax2(E1p[g], E2p[g], f1_[2], f2_[2])           \
                             & __builtin_amdgcn_perm(0u, m2_, 0x01010000u)); \
            fr_.w[3] = (int)(pmax2(E1p[g], E2p[g], f1_[3], f2_[3])           \
                             & __builtin_amdgcn_perm(0u, m2_, 0x03030202u)); \
            accW[g][0] = mfma16(fr_.h, P##h[0], accW[g][0]);                 \
            accW[g][1] = mfma16(fr_.h, P##h[1], accW[g][1]);                 \
            accW[g][2] = mfma16(fr_.h, P##h[2], accW[g][2]);                 \
            accW[g][3] = mfma16(fr_.h, P##h[3], accW[g][3]);                 \
            accZ[g]    = mfma16(fr_.h, ones,  accZ[g]);                      \
        }                                                                    \
    }

    GAT_LOADH(A, 0)
    for (int t = 0; t < 30; t += 2) {
        GAT_LOADH(B, t + 1)
        GAT_COMP(A, t)
        GAT_LOADH(A, t + 2)
        GAT_COMP(B, t + 1)
    }
    GAT_LOADH(B, 31)
    GAT_COMP(A, 30)
    GAT_COMP(B, 31)
#undef GAT_LOADH
#undef GAT_COMP

    __syncthreads();
    {
        float* xb = xch + ((size_t)(wv >> 1) * 64 + l) * 81;
        if (wv & 1) {
#pragma unroll
            for (int g = 0; g < 4; ++g) {
#pragma unroll
                for (int nt = 0; nt < 4; ++nt)
#pragma unroll
                    for (int r = 0; r < 4; ++r) xb[(g * 4 + nt) * 4 + r] = accW[g][nt][r];
#pragma unroll
                for (int r = 0; r < 4; ++r) xb[64 + g * 4 + r] = accZ[g][r];
            }
        }
        __syncthreads();
        if (!(wv & 1)) {
#pragma unroll
            for (int g = 0; g < 4; ++g) {
#pragma unroll
                for (int nt = 0; nt < 4; ++nt)
#pragma unroll
                    for (int r = 0; r < 4; ++r) accW[g][nt][r] += xb[(g * 4 + nt) * 4 + r];
#pragma unroll
                for (int r = 0; r < 4; ++r) accZ[g][r] += xb[64 + g * 4 + r];
            }
        }
        __syncthreads();
        float* x0 = xch + (size_t)l * 81;
        if (wv == 2) {
#pragma unroll
            for (int g = 0; g < 4; ++g) {
#pragma unroll
                for (int nt = 0; nt < 4; ++nt)
#pragma unroll
                    for (int r = 0; r < 4; ++r) x0[(g * 4 + nt) * 4 + r] = accW[g][nt][r];
#pragma unroll
                for (int r = 0; r < 4; ++r) x0[64 + g * 4 + r] = accZ[g][r];
            }
        }
        __syncthreads();
        if (wv == 0) {
#pragma unroll
            for (int g = 0; g < 4; ++g) {
#pragma unroll
                for (int nt = 0; nt < 4; ++nt)
#pragma unroll
                    for (int r = 0; r < 4; ++r) accW[g][nt][r] += x0[(g * 4 + nt) * 4 + r];
#pragma unroll
                for (int r = 0; r < 4; ++r) accZ[g][r] += x0[64 + g * 4 + r];
            }
#pragma unroll
            for (int g = 0; g < 4; ++g) {
                float zi[4];
#pragma unroll
                for (int r = 0; r < 4; ++r) zi[r] = 1.0f / accZ[g][r];
#pragma unroll
                for (int nt = 0; nt < 4; ++nt) {
                    const int col = head * 64 + nt * 16 + dlow;
                    const float b = bias[col];
#pragma unroll
                    for (int r = 0; r < 4; ++r) {
                        const int row = ibase + g * 16 + q * 4 + r;
                        out[(size_t)row * GAT_C + col] = accW[g][nt][r] * zi[r] + b;
                    }
                }
            }
        }
    }
}

extern "C" void kernel_launch(void* const* d_in, const int* in_sizes, int n_in,
                              void* d_out, int out_size, void* d_ws, size_t ws_size,
                              hipStream_t stream) {
    const float* x    = (const float*)d_in[0];
    const int*   adj  = (const int*)d_in[1];
    const float* W    = (const float*)d_in[2];
    const float* asrc = (const float*)d_in[3];
    const float* adst = (const float*)d_in[4];
    const float* bias = (const float*)d_in[5];
    float* out = (float*)d_out;

    char* ws = (char*)d_ws;                     // needs ~7 MB
    _Float16* Hpack  = (_Float16*)ws;                               // 4 MB
    unsigned* maskw  = (unsigned*)(ws + (4u << 20));                // 2 MB
    float*    ddata  = (float*)(ws + (6u << 20));                   // 128 KB
    float*    esrc   = (float*)(ws + (6u << 20) + (128u << 10));    // 128 KB
    unsigned* Epk1   = (unsigned*)(ws + (6u << 20) + (256u << 10)); // 128 KB
    unsigned* Epk2   = (unsigned*)(ws + (6u << 20) + (384u << 10)); // 128 KB
    _Float16* F1     = (_Float16*)(ws + (6u << 20) + (512u << 10)); // 64 KB
    _Float16* F2     = (_Float16*)(ws + (6u << 20) + (576u << 10)); // 64 KB
    _Float16* Wh     = (_Float16*)(ws + (6u << 20) + (640u << 10)); // 256 KB

    hipLaunchKernelGGL(gat_wcvt, dim3(64), dim3(256), 0, stream, W, Wh);
    hipLaunchKernelGGL(gat_prep, dim3(2560), dim3(256), 0, stream,
                       x, Wh, asrc, adst, adj, Hpack, ddata, esrc, maskw);
    hipLaunchKernelGGL(gat_ftab, dim3(128), dim3(256), 0, stream,
                       esrc, ddata, Epk1, Epk2, F1, F2);
    hipLaunchKernelGGL(gat_attn, dim3(512), dim3(256), 0, stream,
                       maskw, Hpack, Epk1, Epk2, F1, F2, bias, out);
}